// Round 11
// baseline (871.738 us; speedup 1.0000x reference)
//
#include <hip/hip_runtime.h>

// Masked dot-product attention, fp32 in/out, bf16 MFMA compute.
// B=8, H=16 (BH=128), Q=K=1024, D=64. valid_lens per batch (int32 on device).
// R11: QW=32 (wave owns 32 q rows, NW=4) -> each ds_read_b128 feeds 2 MFMAs;
//      DS-pipe traffic per unit work halved (R10 diagnosis: DS-bound floor).
//      Keeps: swapped QK^T + bpermute P redistribution, masked-tile skip,
//      LDS dbuf 1 barrier/tile, register prefetch, balanced 1D grid.

#define H_PER_B 16
#define QL 1024
#define KL 1024
#define DH 64
#define KT 64            // keys per KV tile
#define QW 32            // q rows per wave
#define NW 4             // waves per block
#define QB (QW * NW)     // 128 q rows per block
#define KST 72           // Ks row stride (shorts), 144 B: b128 reads hit 8/bank (min)
#define VST 72           // VsT row stride (shorts)

typedef float  f32x4  __attribute__((ext_vector_type(4)));
typedef short  bf16x8 __attribute__((ext_vector_type(8)));
typedef short  bf16x4 __attribute__((ext_vector_type(4)));

__device__ __forceinline__ unsigned bfbits(float f) {   // RNE, bits in low 16
    unsigned u = __builtin_bit_cast(unsigned, f);
    u += 0x7FFFu + ((u >> 16) & 1u);
    return u >> 16;
}
__device__ __forceinline__ unsigned pk2(float a, float b) {
    return bfbits(a) | (bfbits(b) << 16);
}

__global__ __launch_bounds__(256, 4) void attn_fwd(
    const float* __restrict__ Q, const float* __restrict__ K,
    const float* __restrict__ V, const int* __restrict__ vlen_p,
    float* __restrict__ O)
{
    const int id    = blockIdx.x;
    const int qtile = id & 7;       // CU's co-resident blocks span 4 batches
    const int bh    = id >> 3;
    const int vlen  = vlen_p[bh / H_PER_B];

    const int tid  = threadIdx.x;
    const int wave = tid >> 6;             // 0..3
    const int lane = tid & 63;
    const int lg   = lane >> 4;            // 0..3
    const int lr   = lane & 15;            // 0..15

    const float* Qb = Q + ((size_t)bh * QL + (size_t)qtile * QB + (size_t)wave * QW) * DH;
    const float* Kb = K + (size_t)bh * KL * DH;
    const float* Vb = V + (size_t)bh * KL * DH;

    __shared__ short Ks [2][KT][KST];      // K tile, bf16 row-major [k][d]
    __shared__ short VsT[2][DH][VST];      // V tile, bf16 transposed [d][k]

    // --- Q fragments (B-operand layout), scale 1/8*log2(e) folded in ---
    const float QSCALE = 0.18033688011112042f;   // 0.125 * log2(e); p = exp2(s)
    bf16x8 qf[2][2];                       // [dc][qh]
#pragma unroll
    for (int qh = 0; qh < 2; ++qh)
#pragma unroll
    for (int dc = 0; dc < 2; ++dc) {
        const float* p = Qb + (size_t)(qh * 16 + lr) * DH + dc * 32 + 8 * lg;
        float4 a = *(const float4*)p;
        float4 b = *(const float4*)(p + 4);
        uint4 u;
        u.x = pk2(a.x * QSCALE, a.y * QSCALE);
        u.y = pk2(a.z * QSCALE, a.w * QSCALE);
        u.z = pk2(b.x * QSCALE, b.y * QSCALE);
        u.w = pk2(b.z * QSCALE, b.w * QSCALE);
        qf[dc][qh] = __builtin_bit_cast(bf16x8, u);
    }

    f32x4 acc[4][2];                       // [dt][qh]
#pragma unroll
    for (int i = 0; i < 4; ++i)
#pragma unroll
        for (int qh = 0; qh < 2; ++qh) acc[i][qh] = (f32x4){0.f, 0.f, 0.f, 0.f};
    float lsum[2] = {0.f, 0.f};

    const bool  all_masked = (vlen == 0);
    const float msel       = all_masked ? 1.0f : 0.0f;
    // Fully-masked K tiles contribute exactly 0 (exp(-1e6-max) underflows in
    // fp32 in the reference too) -> skip. vlen==0: uniform weights, full loop.
    const int nt = all_masked ? (KL / KT) : ((vlen + KT - 1) >> 6);

    // staging assignments (256 threads stage a 64x64 tile of K and of V)
    const int kr0 = tid >> 4;              // K rows kr0 + 16*i, col chunk dc0
    const int dc0 = (tid & 15) * 4;
    const int vd  = tid & 63;              // V column d, k-chunk [vk0, vk0+16)
    const int vk0 = wave * 16;
    const float* Vcol = Vb + vd;

    float4 ka[4];                          // prefetch registers
    float  va[16];

#define LOADK(t)                                                              \
    _Pragma("unroll")                                                         \
    for (int i = 0; i < 4; ++i)                                               \
        ka[i] = *(const float4*)(Kb + (size_t)((t) * KT + kr0 + 16 * i) * DH + dc0);
#define LOADV(t)                                                              \
    _Pragma("unroll")                                                         \
    for (int j = 0; j < 16; ++j)                                              \
        va[j] = Vcol[(size_t)((t) * KT + vk0 + j) * DH];
#define STOREKV(b)                                                            \
    {                                                                         \
        _Pragma("unroll")                                                     \
        for (int i = 0; i < 4; ++i) {                                         \
            uint2 kk = {pk2(ka[i].x, ka[i].y), pk2(ka[i].z, ka[i].w)};        \
            *(bf16x4*)&Ks[b][kr0 + 16 * i][dc0] =                             \
                __builtin_bit_cast(bf16x4, kk);                               \
        }                                                                     \
        uint4 v0 = {pk2(va[0], va[1]),  pk2(va[2], va[3]),                    \
                    pk2(va[4], va[5]),  pk2(va[6], va[7])};                   \
        uint4 v1 = {pk2(va[8], va[9]),  pk2(va[10], va[11]),                  \
                    pk2(va[12], va[13]), pk2(va[14], va[15])};                \
        *(bf16x8*)&VsT[b][vd][vk0]     = __builtin_bit_cast(bf16x8, v0);      \
        *(bf16x8*)&VsT[b][vd][vk0 + 8] = __builtin_bit_cast(bf16x8, v1);      \
    }

    // bpermute addressing for the P redistribution:
    // target lane (lg,lr) pulls D0/D1 from src lane 32*(lg&1)+lr, D2/D3 from
    // src+16, selecting packed group a = 2u + (lg>>1).
    const int addr0 = (((lane & 16) << 1) | (lane & 15)) << 2;
    const int addr1 = addr0 + 64;
    const bool selhi = (lane & 32) != 0;

    // prologue: stage tile 0
    LOADK(0); LOADV(0); STOREKV(0);

    for (int t = 0; t < nt; ++t) {
        const int buf = t & 1;
        __syncthreads();                   // buf[t&1] staged by all waves

        if (t + 1 < nt) { LOADK(t + 1); LOADV(t + 1); }   // issue early
        const int kt0 = t * KT;

        // --- S^T = K Q^T: lane holds S[q-half][k = kt0+16kh+4lg+r], q=lr ---
        unsigned d0[2][4], d1[2][4];       // [qh][kh], packed bf16 pairs
#pragma unroll
        for (int kh = 0; kh < 4; ++kh) {
            f32x4 c0 = (f32x4){0.f, 0.f, 0.f, 0.f};
            f32x4 c1 = (f32x4){0.f, 0.f, 0.f, 0.f};
#pragma unroll
            for (int dc = 0; dc < 2; ++dc) {
                bf16x8 kf = *(const bf16x8*)&Ks[buf][kh * 16 + lr][dc * 32 + 8 * lg];
                c0 = __builtin_amdgcn_mfma_f32_16x16x32_bf16(kf, qf[dc][0], c0, 0, 0, 0);
                c1 = __builtin_amdgcn_mfma_f32_16x16x32_bf16(kf, qf[dc][1], c1, 0, 0, 0);
            }
            const int kbase = kt0 + kh * 16 + 4 * lg;
            float p0[4], p1[4];
#pragma unroll
            for (int r = 0; r < 4; ++r) {
                const bool m = (kbase + r >= vlen);
                float e0 = __builtin_amdgcn_exp2f(c0[r]);
                float e1 = __builtin_amdgcn_exp2f(c1[r]);
                p0[r] = m ? msel : e0;  lsum[0] += p0[r];
                p1[r] = m ? msel : e1;  lsum[1] += p1[r];
            }
            d0[0][kh] = pk2(p0[0], p0[1]);  d1[0][kh] = pk2(p0[2], p0[3]);
            d0[1][kh] = pk2(p1[0], p1[1]);  d1[1][kh] = pk2(p1[2], p1[3]);
        }

        // --- redistribute P to A-frag layout + PV (vf shared by both qh) ---
#pragma unroll
        for (int u = 0; u < 2; ++u) {
            const int a0 = 2 * u, a1 = 2 * u + 1;
            bf16x8 pf[2];
#pragma unroll
            for (int qh = 0; qh < 2; ++qh) {
                int lo, hi;
                uint4 Dv;
                lo = __builtin_amdgcn_ds_bpermute(addr0, (int)d0[qh][a0]);
                hi = __builtin_amdgcn_ds_bpermute(addr0, (int)d0[qh][a1]);
                Dv.x = (unsigned)(selhi ? hi : lo);
                lo = __builtin_amdgcn_ds_bpermute(addr0, (int)d1[qh][a0]);
                hi = __builtin_amdgcn_ds_bpermute(addr0, (int)d1[qh][a1]);
                Dv.y = (unsigned)(selhi ? hi : lo);
                lo = __builtin_amdgcn_ds_bpermute(addr1, (int)d0[qh][a0]);
                hi = __builtin_amdgcn_ds_bpermute(addr1, (int)d0[qh][a1]);
                Dv.z = (unsigned)(selhi ? hi : lo);
                lo = __builtin_amdgcn_ds_bpermute(addr1, (int)d1[qh][a0]);
                hi = __builtin_amdgcn_ds_bpermute(addr1, (int)d1[qh][a1]);
                Dv.w = (unsigned)(selhi ? hi : lo);
                pf[qh] = __builtin_bit_cast(bf16x8, Dv);  // P[lr][u*32+8lg+0..7]
            }
#pragma unroll
            for (int dt = 0; dt < 4; ++dt) {
                bf16x8 vf = *(const bf16x8*)&VsT[buf][dt * 16 + lr][u * 32 + 8 * lg];
                acc[dt][0] = __builtin_amdgcn_mfma_f32_16x16x32_bf16(pf[0], vf, acc[dt][0], 0, 0, 0);
                acc[dt][1] = __builtin_amdgcn_mfma_f32_16x16x32_bf16(pf[1], vf, acc[dt][1], 0, 0, 0);
            }
        }

        if (t + 1 < nt) STOREKV((t + 1) & 1);   // other buffer; safe post-barrier
    }

    // --- epilogue per q-half: reduce denom, redistribute inv, store ---
    float* Ob = O + ((size_t)bh * QL + (size_t)qtile * QB + (size_t)wave * QW) * DH;
#pragma unroll
    for (int qh = 0; qh < 2; ++qh) {
        float sum = lsum[qh] + __shfl_xor(lsum[qh], 16, 64);
        sum += __shfl_xor(sum, 32, 64);
        const float inv = 1.0f / sum;      // all lanes: inv for q-row = lr
        float invr[4];
#pragma unroll
        for (int r = 0; r < 4; ++r) {
            int a = (lane & 48) + 4 * r;   // byte addr -> src lane 4*lg + r
            invr[r] = __builtin_bit_cast(float,
                        __builtin_amdgcn_ds_bpermute(a, __builtin_bit_cast(int, inv)));
        }
#pragma unroll
        for (int r = 0; r < 4; ++r)
#pragma unroll
            for (int dt = 0; dt < 4; ++dt)
                Ob[(size_t)(qh * 16 + lg * 4 + r) * DH + dt * 16 + lr] =
                    acc[dt][qh][r] * invr[r];
    }
}

extern "C" void kernel_launch(void* const* d_in, const int* in_sizes, int n_in,
                              void* d_out, int out_size, void* d_ws, size_t ws_size,
                              hipStream_t stream) {
    (void)in_sizes; (void)n_in; (void)d_ws; (void)ws_size; (void)out_size;
    const float* Q    = (const float*)d_in[0];
    const float* K    = (const float*)d_in[1];
    const float* V    = (const float*)d_in[2];
    const int*   vlen = (const int*)d_in[3];
    float*       O    = (float*)d_out;

    dim3 grid(128 * (QL / QB));   // 1024 blocks, id&7 = qtile for load balance
    dim3 block(256);              // 4 waves
    attn_fwd<<<grid, block, 0, stream>>>(Q, K, V, vlen, O);
}